// Round 17
// baseline (3047.569 us; speedup 1.0000x reference)
//
#include <hip/hip_runtime.h>
#include <hip/hip_bf16.h>
#include <cstdint>
#include <cstddef>

// ws layout (float offsets)
#define WS_BMAT 0            // bmatT: 24*640 = 15360
#define WS_BBIG 15360        // 24 (+pad to 64)
#define WS_WBT  15424        // wbT bf16 [32][3072] = 98304 ushort = 49152 floats
#define WS_ND   64576        // 8*8192*23 = 1507328
#define WS_ED   1571904      // 4*28672*23 = 2637824  (end 4209728 floats)

// output offsets (floats)
#define OUT_IND 0
#define OUT_LAB 28672
#define OUT_LRP 57344
#define OUT_CRP 98304
#define OUT_MRP 122880
#define OUT_LRN 237568
#define OUT_CRN 339968
#define OUT_MRN 401408

typedef __attribute__((ext_vector_type(8))) short bf16x8;
typedef __attribute__((ext_vector_type(4))) float f32x4;

__device__ __constant__ int d_pi[28] = {0,0,0,0,0,0,0,1,1,1,1,1,1,2,2,2,2,2,3,3,3,3,4,4,4,5,5,6};
__device__ __constant__ int d_pj[28] = {1,2,3,4,5,6,7,2,3,4,5,6,7,3,4,5,6,7,4,5,6,7,5,6,7,6,7,7};

__device__ __forceinline__ float wh_at(const float* wlr, const float* wcr, const float* wmr,
                                       int j, int h) {
  return (h < 5) ? wlr[j*5 + h] : (h < 8) ? wcr[j*3 + (h-5)] : wmr[j*14 + (h-8)];
}

__device__ __forceinline__ short f2bf(float f) {
  __hip_bfloat16 h = __float2bfloat16(f);
  short s;
  __builtin_memcpy(&s, &h, 2);
  return s;
}
__device__ __forceinline__ unsigned int f2bfu(float f) {
  __hip_bfloat16 h = __float2bfloat16(f);
  unsigned short s;
  __builtin_memcpy(&s, &h, 2);
  return (unsigned int)s;
}

// ================= bodies (shared by production and diag kernels) =================

__device__ __forceinline__ void prep1_body(
    const float* __restrict__ w_rel, const float* __restrict__ w_ind2,
    const float* __restrict__ w_lr, const float* __restrict__ w_cr, const float* __restrict__ w_mr,
    const float* __restrict__ b_ind1, const float* __restrict__ b_ind2,
    const float* __restrict__ b_rel,
    const float* __restrict__ b_lr, const float* __restrict__ b_cr, const float* __restrict__ b_mr,
    float* __restrict__ bmat, float* __restrict__ bbig) {
  int bid = blockIdx.x, tid = threadIdx.x;
  if (bid < 128) {
    int m = bid;
    __shared__ float swr[512];
    const float* wr2 = w_rel + (size_t)(3072 + m)*512;
    swr[tid]       = wr2[tid];
    swr[tid + 256] = wr2[tid + 256];
    __syncthreads();
    int h = tid >> 3, q = tid & 7;
    if (h < 22) {
      float a = 0.f;
#pragma unroll 8
      for (int jj = 0; jj < 64; ++jj) {
        int j = jj*8 + q;
        a = fmaf(swr[j], wh_at(w_lr, w_cr, w_mr, j, h), a);
      }
      a += __shfl_xor(a, 1); a += __shfl_xor(a, 2); a += __shfl_xor(a, 4);
      if (q == 0) bmat[(1 + h)*640 + m] = a;
    }
    if (tid == 248) bmat[0*640 + m]  = w_ind2[m];
    if (tid == 249) bmat[23*640 + m] = 0.f;
    __syncthreads();                       // rep-safe: swr reuse
  } else if (bid == 128) {
    __shared__ float sbrel[512];
    for (int j = tid; j < 512; j += 256) {
      float a = b_rel[j];
#pragma unroll 4
      for (int m = 0; m < 128; ++m)
        a = fmaf(b_ind1[m], w_rel[(size_t)(3072 + m)*512 + j], a);
      sbrel[j] = a;
    }
    __syncthreads();
    int h = tid >> 3, q = tid & 7;
    if (h < 22) {
      float bh = (h < 5) ? b_lr[h] : (h < 8) ? b_cr[h-5] : b_mr[h-8];
      float a = 0.f;
#pragma unroll 8
      for (int jj = 0; jj < 64; ++jj) {
        int j = jj*8 + q;
        a = fmaf(sbrel[j], wh_at(w_lr, w_cr, w_mr, j, h), a);
      }
      a += __shfl_xor(a, 1); a += __shfl_xor(a, 2); a += __shfl_xor(a, 4);
      if (q == 0) bbig[1 + h] = a + bh;
    } else if (tid >= 248) {
      int q2 = tid & 7;
      float a = 0.f;
#pragma unroll
      for (int t = 0; t < 16; ++t)
        a = fmaf(b_ind1[q2*16 + t], w_ind2[q2*16 + t], a);
      a += __shfl_xor(a, 1); a += __shfl_xor(a, 2); a += __shfl_xor(a, 4);
      if (tid == 248) bbig[0]  = a + b_ind2[0];
      if (tid == 250) bbig[23] = 0.f;
    }
    __syncthreads();
  } else {
    int idx = (bid - 129)*256 + tid;
    int j = idx / 24, n = idx % 24;
    float v = (n >= 1 && n <= 22) ? wh_at(w_lr, w_cr, w_mr, j, n - 1) : 0.f;
    bmat[n*640 + 128 + j] = v;
  }
}

__device__ __forceinline__ void prep2_body(
    const float* __restrict__ w_ind1, const float* __restrict__ w_rel,
    const float* __restrict__ bmat, unsigned int* __restrict__ wbT32) {
  int g = blockIdx.x*256 + threadIdx.x;
  int gid = g >> 2, q = g & 3;
  int kp = gid & 1, n = (gid >> 1) & 31, k2 = gid >> 6;
  int k = k2*2 + kp;
  float a = 0.f;
  if (n < 23) {
    const float* wr = w_rel + (size_t)k*512;
    const float* bn = bmat + n*640;
    if (q == 0) {
      const float* w1 = w_ind1 + (size_t)k*128;
#pragma unroll 8
      for (int i = 0; i < 128; ++i) a = fmaf(w1[i], bn[i], a);
#pragma unroll 8
      for (int j = 0; j < 32; ++j) a = fmaf(wr[j], bn[128 + j], a);
    } else {
      int j0 = 32 + (q - 1)*160;
#pragma unroll 8
      for (int jj = 0; jj < 160; ++jj) {
        int j = j0 + jj;
        a = fmaf(wr[j], bn[128 + j], a);
      }
    }
  }
  a += __shfl_xor(a, 1); a += __shfl_xor(a, 2);
  float other = __shfl_xor(a, 4);
  if (q == 0 && kp == 0) {
    unsigned int lo = f2bfu(a), hi = f2bfu(other);
    wbT32[(size_t)n*1536 + k2] = lo | (hi << 16);
  }
}

// R13 kmain body: one independent wave-job = 64 rows x 256 k (verified-correct MFMA).
__device__ __forceinline__ void kmain_body(
    const float* __restrict__ nf, const float* __restrict__ intf,
    const unsigned short* __restrict__ wbT, float* __restrict__ ndp, float* __restrict__ edp,
    float (*red)[1600]) {
  const int tid = threadIdx.x;
  const int l = tid & 63;
  const int w = tid >> 6;
  const int wid = blockIdx.x*4 + w;
  const bool isNode = wid < 1024;

  int rg, chunk, kbase;
  if (isNode) { rg = wid >> 3; chunk = wid & 7; kbase = 0; }
  else        { int e = wid - 1024; rg = e >> 2; chunk = e & 3; kbase = 2048; }
  const int R0 = rg*64;
  const int kd0 = chunk*256;

  const int ln = l & 15, lg = l >> 4;

  const float* xp[4];
#pragma unroll
  for (int i = 0; i < 4; ++i) {
    int grow = R0 + i*16 + ln;
    const float* rp;
    if (isNode) rp = nf + (size_t)grow*2048;
    else {
      int b = grow / 28, p = grow - b*28;
      rp = intf + (size_t)(b*64 + d_pi[p]*8 + d_pj[p])*1024;
    }
    xp[i] = rp + kd0 + lg*8;
  }
  const unsigned short* wp0 = wbT + (size_t)ln*3072 + kbase + kd0 + lg*8;
  const unsigned short* wp1 = wp0 + (size_t)16*3072;

  f32x4 acc[4][2];
#pragma unroll
  for (int i = 0; i < 4; ++i) {
    acc[i][0] = (f32x4){0.f, 0.f, 0.f, 0.f};
    acc[i][1] = (f32x4){0.f, 0.f, 0.f, 0.f};
  }

#pragma unroll 2
  for (int t = 0; t < 8; ++t) {
    const int ko = t*32;
    bf16x8 b0 = *(const bf16x8*)(wp0 + ko);
    bf16x8 b1 = *(const bf16x8*)(wp1 + ko);
#pragma unroll
    for (int i = 0; i < 4; ++i) {
      float4 xa = *(const float4*)(xp[i] + ko);
      float4 xb = *(const float4*)(xp[i] + ko + 4);
      bf16x8 a;
      a[0] = f2bf(xa.x); a[1] = f2bf(xa.y); a[2] = f2bf(xa.z); a[3] = f2bf(xa.w);
      a[4] = f2bf(xb.x); a[5] = f2bf(xb.y); a[6] = f2bf(xb.z); a[7] = f2bf(xb.w);
      acc[i][0] = __builtin_amdgcn_mfma_f32_16x16x32_bf16(a, b0, acc[i][0], 0, 0, 0);
      acc[i][1] = __builtin_amdgcn_mfma_f32_16x16x32_bf16(a, b1, acc[i][1], 0, 0, 0);
    }
  }

  float* rw = red[w];
#pragma unroll
  for (int i = 0; i < 4; ++i)
#pragma unroll
    for (int tn = 0; tn < 2; ++tn) {
      int n = tn*16 + ln;
      if (n < 23) {
#pragma unroll
        for (int r = 0; r < 4; ++r)
          rw[(i*16 + lg*4 + r)*25 + n] = acc[i][tn][r];
      }
    }
  __syncthreads();
  float* outp = isNode ? (ndp + ((size_t)chunk*8192  + R0)*23)
                       : (edp + ((size_t)chunk*28672 + R0)*23);
#pragma unroll
  for (int i = 0; i < 23; ++i) {
    int g = i*64 + l;
    int r = g / 23, n = g - r*23;
    outp[g] = rw[r*25 + n];
  }
  __syncthreads();                         // rep-safe: red reuse
}

__device__ __forceinline__ void kcombine_body(
    const float* __restrict__ ndp, const float* __restrict__ edp,
    const float* __restrict__ bbig, const int* __restrict__ opairs,
    float* __restrict__ out) {
  __shared__ float snd[184];
  __shared__ int spos[8];
  int b = blockIdx.x, tid = threadIdx.x;
  if (tid < 184) {
    int o = tid / 23, n = tid % 23;
    float s = 0.f;
#pragma unroll
    for (int c = 0; c < 8; ++c)
      s += ndp[((size_t)c*8192 + b*8 + o)*23 + n];
    snd[tid] = s;
  } else if (tid < 192) {
    int r = tid - 184;
    int oi = opairs[b*16 + r*2], oj = opairs[b*16 + r*2 + 1];
    int a = min(oi, oj), bb = max(oi, oj);
    spos[r] = 7*a - (a*(a+1))/2 + bb - 1;
  }
  __syncthreads();
  for (int g = tid; g < 644; g += 256) {
    int p = g / 23, n = g % 23;
    float ed = 0.f;
#pragma unroll
    for (int c = 0; c < 4; ++c)
      ed += edp[((size_t)c*28672 + b*28 + p)*23 + n];
    float val = 0.5f*(snd[d_pi[p]*23 + n] + snd[d_pj[p]*23 + n]) + ed + bbig[n];
    int slot = -1, below = 0;
#pragma unroll
    for (int r = 0; r < 8; ++r) {
      int pl = spos[r];
      slot = (pl == p) ? r : slot;
      below += (pl < p) ? 1 : 0;
    }
    if (n == 0) {
      out[OUT_IND + b*28 + p] = 1.f/(1.f + expf(-val));
      out[OUT_LAB + b*28 + p] = (slot >= 0) ? 1.f : 0.f;
    } else {
      int h = n - 1;
      if (slot >= 0) {
        int rr = b*8 + slot;
        if (h < 5)      out[OUT_LRP + rr*5  + h]     = val;
        else if (h < 8) out[OUT_CRP + rr*3  + (h-5)] = val;
        else            out[OUT_MRP + rr*14 + (h-8)] = val;
      } else {
        int s = p - below;
        int rr = b*20 + s;
        if (h < 5)      out[OUT_LRN + rr*5  + h]     = val;
        else if (h < 8) out[OUT_CRN + rr*3  + (h-5)] = val;
        else            out[OUT_MRN + rr*14 + (h-8)] = val;
      }
    }
  }
  __syncthreads();                         // rep-safe: snd reuse
}

// ================= production kernels =================
__global__ __launch_bounds__(256) void prep1(
    const float* __restrict__ w_rel, const float* __restrict__ w_ind2,
    const float* __restrict__ w_lr, const float* __restrict__ w_cr, const float* __restrict__ w_mr,
    const float* __restrict__ b_ind1, const float* __restrict__ b_ind2,
    const float* __restrict__ b_rel,
    const float* __restrict__ b_lr, const float* __restrict__ b_cr, const float* __restrict__ b_mr,
    float* __restrict__ bmat, float* __restrict__ bbig) {
  prep1_body(w_rel, w_ind2, w_lr, w_cr, w_mr, b_ind1, b_ind2, b_rel, b_lr, b_cr, b_mr, bmat, bbig);
}

__global__ __launch_bounds__(256) void prep2(
    const float* __restrict__ w_ind1, const float* __restrict__ w_rel,
    const float* __restrict__ bmat, unsigned int* __restrict__ wbT32) {
  prep2_body(w_ind1, w_rel, bmat, wbT32);
}

__global__ __launch_bounds__(256) void kmain_mfma(
    const float* __restrict__ nf, const float* __restrict__ intf,
    const unsigned short* __restrict__ wbT, float* __restrict__ ndp, float* __restrict__ edp) {
  __shared__ float red[4][1600];
  kmain_body(nf, intf, wbT, ndp, edp, red);
}

__global__ __launch_bounds__(256) void kcombine(
    const float* __restrict__ ndp, const float* __restrict__ edp,
    const float* __restrict__ bbig, const int* __restrict__ opairs,
    float* __restrict__ out) {
  kcombine_body(ndp, edp, bbig, opairs, out);
}

// ================= diagnostic amplified clones (identical work x reps) =================
__global__ __launch_bounds__(256) void prep1_diag(
    const float* __restrict__ w_rel, const float* __restrict__ w_ind2,
    const float* __restrict__ w_lr, const float* __restrict__ w_cr, const float* __restrict__ w_mr,
    const float* __restrict__ b_ind1, const float* __restrict__ b_ind2,
    const float* __restrict__ b_rel,
    const float* __restrict__ b_lr, const float* __restrict__ b_cr, const float* __restrict__ b_mr,
    float* __restrict__ bmat, float* __restrict__ bbig) {
#pragma unroll 1
  for (int rep = 0; rep < 48; ++rep) {
    prep1_body(w_rel, w_ind2, w_lr, w_cr, w_mr, b_ind1, b_ind2, b_rel, b_lr, b_cr, b_mr, bmat, bbig);
    asm volatile("" ::: "memory");
  }
}

__global__ __launch_bounds__(256) void prep2_diag(
    const float* __restrict__ w_ind1, const float* __restrict__ w_rel,
    const float* __restrict__ bmat, unsigned int* __restrict__ wbT32) {
#pragma unroll 1
  for (int rep = 0; rep < 48; ++rep) {
    prep2_body(w_ind1, w_rel, bmat, wbT32);
    asm volatile("" ::: "memory");
  }
}

__global__ __launch_bounds__(256) void kmain_diag(
    const float* __restrict__ nf, const float* __restrict__ intf,
    const unsigned short* __restrict__ wbT, float* __restrict__ ndp, float* __restrict__ edp) {
  __shared__ float red[4][1600];
#pragma unroll 1
  for (int rep = 0; rep < 8; ++rep) {
    kmain_body(nf, intf, wbT, ndp, edp, red);
    asm volatile("" ::: "memory");
  }
}

__global__ __launch_bounds__(256) void kcombine_diag(
    const float* __restrict__ ndp, const float* __restrict__ edp,
    const float* __restrict__ bbig, const int* __restrict__ opairs,
    float* __restrict__ out) {
#pragma unroll 1
  for (int rep = 0; rep < 48; ++rep) {
    kcombine_body(ndp, edp, bbig, opairs, out);
    asm volatile("" ::: "memory");
  }
}

extern "C" void kernel_launch(void* const* d_in, const int* in_sizes, int n_in,
                              void* d_out, int out_size, void* d_ws, size_t ws_size,
                              hipStream_t stream) {
  const float* nf     = (const float*)d_in[0];
  const float* intf   = (const float*)d_in[1];
  const int*   opairs = (const int*)d_in[2];
  const float* w_ind1 = (const float*)d_in[3];
  const float* b_ind1 = (const float*)d_in[4];
  const float* w_ind2 = (const float*)d_in[5];
  const float* b_ind2 = (const float*)d_in[6];
  const float* w_rel  = (const float*)d_in[7];
  const float* b_rel  = (const float*)d_in[8];
  const float* w_cr   = (const float*)d_in[9];
  const float* b_cr   = (const float*)d_in[10];
  const float* w_lr   = (const float*)d_in[11];
  const float* b_lr   = (const float*)d_in[12];
  const float* w_mr   = (const float*)d_in[13];
  const float* b_mr   = (const float*)d_in[14];
  float* out = (float*)d_out;
  float* ws  = (float*)d_ws;

  float*          bmat  = ws + WS_BMAT;
  float*          bbig  = ws + WS_BBIG;
  unsigned int*   wbT32 = (unsigned int*)(ws + WS_WBT);
  unsigned short* wbT   = (unsigned short*)(ws + WS_WBT);
  float*          ndp   = ws + WS_ND;
  float*          edp   = ws + WS_ED;

  // production pipeline (R13, best passing config)
  prep1<<<177, 256, 0, stream>>>(w_rel, w_ind2, w_lr, w_cr, w_mr,
                                 b_ind1, b_ind2, b_rel, b_lr, b_cr, b_mr, bmat, bbig);
  prep2<<<1536, 256, 0, stream>>>(w_ind1, w_rel, bmat, wbT32);
  kmain_mfma<<<704, 256, 0, stream>>>(nf, intf, wbT, ndp, edp);
  kcombine<<<1024, 256, 0, stream>>>(ndp, edp, bbig, opairs, out);

  // attribution diagnostics (identical work, amplified; outputs reproduce same values)
  prep1_diag<<<177, 256, 0, stream>>>(w_rel, w_ind2, w_lr, w_cr, w_mr,
                                      b_ind1, b_ind2, b_rel, b_lr, b_cr, b_mr, bmat, bbig);
  prep2_diag<<<1536, 256, 0, stream>>>(w_ind1, w_rel, bmat, wbT32);
  kmain_diag<<<704, 256, 0, stream>>>(nf, intf, wbT, ndp, edp);
  kcombine_diag<<<1024, 256, 0, stream>>>(ndp, edp, bbig, opairs, out);
}

// Round 18
// 108.505 us; speedup vs baseline: 28.0870x; 28.0870x over previous
//
#include <hip/hip_runtime.h>
#include <hip/hip_bf16.h>
#include <cstdint>
#include <cstddef>

// ws layout (float offsets)
#define WS_BMAT 0            // bmatT: 24*640 = 15360
#define WS_BBIG 15360        // 24 (+pad to 64)
#define WS_WBT  15424        // wbT bf16 [32][3072] = 98304 ushort = 49152 floats
#define WS_ND   64576        // 8*8192*23 = 1507328
#define WS_ED   1571904      // 4*28672*23 = 2637824  (end 4209728 floats)

// output offsets (floats)
#define OUT_IND 0
#define OUT_LAB 28672
#define OUT_LRP 57344
#define OUT_CRP 98304
#define OUT_MRP 122880
#define OUT_LRN 237568
#define OUT_CRN 339968
#define OUT_MRN 401408

typedef __attribute__((ext_vector_type(8))) short bf16x8;
typedef __attribute__((ext_vector_type(4))) float f32x4;

__device__ __constant__ int d_pi[28] = {0,0,0,0,0,0,0,1,1,1,1,1,1,2,2,2,2,2,3,3,3,3,4,4,4,5,5,6};
__device__ __constant__ int d_pj[28] = {1,2,3,4,5,6,7,2,3,4,5,6,7,3,4,5,6,7,4,5,6,7,5,6,7,6,7,7};

__device__ __forceinline__ float wh_at(const float* wlr, const float* wcr, const float* wmr,
                                       int j, int h) {
  return (h < 5) ? wlr[j*5 + h] : (h < 8) ? wcr[j*3 + (h-5)] : wmr[j*14 + (h-8)];
}

__device__ __forceinline__ short f2bf(float f) {
  __hip_bfloat16 h = __float2bfloat16(f);
  short s;
  __builtin_memcpy(&s, &h, 2);
  return s;
}
__device__ __forceinline__ unsigned int f2bfu(float f) {
  __hip_bfloat16 h = __float2bfloat16(f);
  unsigned short s;
  __builtin_memcpy(&s, &h, 2);
  return (unsigned int)s;
}

// ---------------- prep1: bmatT[24][640] and b_big ----------------
__global__ __launch_bounds__(256) void prep1(
    const float* __restrict__ w_rel, const float* __restrict__ w_ind2,
    const float* __restrict__ w_lr, const float* __restrict__ w_cr, const float* __restrict__ w_mr,
    const float* __restrict__ b_ind1, const float* __restrict__ b_ind2,
    const float* __restrict__ b_rel,
    const float* __restrict__ b_lr, const float* __restrict__ b_cr, const float* __restrict__ b_mr,
    float* __restrict__ bmat, float* __restrict__ bbig) {
  int bid = blockIdx.x, tid = threadIdx.x;
  if (bid < 128) {
    int m = bid;
    __shared__ float swr[512];
    const float* wr2 = w_rel + (size_t)(3072 + m)*512;
    swr[tid]       = wr2[tid];
    swr[tid + 256] = wr2[tid + 256];
    __syncthreads();
    int h = tid >> 3, q = tid & 7;
    if (h < 22) {
      float a = 0.f;
#pragma unroll 8
      for (int jj = 0; jj < 64; ++jj) {
        int j = jj*8 + q;
        a = fmaf(swr[j], wh_at(w_lr, w_cr, w_mr, j, h), a);
      }
      a += __shfl_xor(a, 1); a += __shfl_xor(a, 2); a += __shfl_xor(a, 4);
      if (q == 0) bmat[(1 + h)*640 + m] = a;
    }
    if (tid == 248) bmat[0*640 + m]  = w_ind2[m];
    if (tid == 249) bmat[23*640 + m] = 0.f;
  } else if (bid == 128) {
    __shared__ float sbrel[512];
    for (int j = tid; j < 512; j += 256) {
      float a = b_rel[j];
#pragma unroll 4
      for (int m = 0; m < 128; ++m)
        a = fmaf(b_ind1[m], w_rel[(size_t)(3072 + m)*512 + j], a);
      sbrel[j] = a;
    }
    __syncthreads();
    int h = tid >> 3, q = tid & 7;
    if (h < 22) {
      float bh = (h < 5) ? b_lr[h] : (h < 8) ? b_cr[h-5] : b_mr[h-8];
      float a = 0.f;
#pragma unroll 8
      for (int jj = 0; jj < 64; ++jj) {
        int j = jj*8 + q;
        a = fmaf(sbrel[j], wh_at(w_lr, w_cr, w_mr, j, h), a);
      }
      a += __shfl_xor(a, 1); a += __shfl_xor(a, 2); a += __shfl_xor(a, 4);
      if (q == 0) bbig[1 + h] = a + bh;
    } else if (tid >= 248) {
      int q2 = tid & 7;
      float a = 0.f;
#pragma unroll
      for (int t = 0; t < 16; ++t)
        a = fmaf(b_ind1[q2*16 + t], w_ind2[q2*16 + t], a);
      a += __shfl_xor(a, 1); a += __shfl_xor(a, 2); a += __shfl_xor(a, 4);
      if (tid == 248) bbig[0]  = a + b_ind2[0];
      if (tid == 250) bbig[23] = 0.f;
    }
  } else {
    int idx = (bid - 129)*256 + tid;
    int j = idx / 24, n = idx % 24;
    float v = (n >= 1 && n <= 22) ? wh_at(w_lr, w_cr, w_mr, j, n - 1) : 0.f;
    bmat[n*640 + 128 + j] = v;
  }
}

// ---------------- prep2 v2: float4 operands + 4 independent acc chains ----------------
// Same decomposition as R13 (4 quarters per output, shfl reduce, packed-pair dword store);
// loads explicitly vectorized (G13: hipcc never auto-vectorizes) -> 80 VMEM instrs/thread
// instead of 320 scalars, dependency depth 160 -> 40.
__global__ __launch_bounds__(256) void prep2(
    const float* __restrict__ w_ind1, const float* __restrict__ w_rel,
    const float* __restrict__ bmat, unsigned int* __restrict__ wbT32) {
  int g = blockIdx.x*256 + threadIdx.x;    // 393216 = 98304 outputs x 4 quarters
  int gid = g >> 2, q = g & 3;
  int kp = gid & 1, n = (gid >> 1) & 31, k2 = gid >> 6;
  int k = k2*2 + kp;
  float a0 = 0.f, a1 = 0.f, a2 = 0.f, a3 = 0.f;
  if (n < 23) {
    // all bases 16B-aligned: k*512, k*128, n*640, n*640+128 are multiples of 4 floats
    const float4* wr4 = (const float4*)(w_rel + (size_t)k*512);          // j 0..511 (post-128)
    const float4* bn4 = (const float4*)(bmat + n*640 + 128);             // bmatT[n][128+j]
    if (q == 0) {
      const float4* w14 = (const float4*)(w_ind1 + (size_t)k*128);
      const float4* bn0 = (const float4*)(bmat + n*640);
#pragma unroll 8
      for (int i = 0; i < 32; ++i) {
        float4 wv = w14[i], bv = bn0[i];
        a0 = fmaf(wv.x, bv.x, a0); a1 = fmaf(wv.y, bv.y, a1);
        a2 = fmaf(wv.z, bv.z, a2); a3 = fmaf(wv.w, bv.w, a3);
      }
#pragma unroll 8
      for (int i = 0; i < 8; ++i) {
        float4 wv = wr4[i], bv = bn4[i];
        a0 = fmaf(wv.x, bv.x, a0); a1 = fmaf(wv.y, bv.y, a1);
        a2 = fmaf(wv.z, bv.z, a2); a3 = fmaf(wv.w, bv.w, a3);
      }
    } else {
      int j4 = 8 + (q - 1)*40;             // float4 index into wr4/bn4: covers j 32..512
#pragma unroll 8
      for (int i = 0; i < 40; ++i) {
        float4 wv = wr4[j4 + i], bv = bn4[j4 + i];
        a0 = fmaf(wv.x, bv.x, a0); a1 = fmaf(wv.y, bv.y, a1);
        a2 = fmaf(wv.z, bv.z, a2); a3 = fmaf(wv.w, bv.w, a3);
      }
    }
  }
  float a = (a0 + a1) + (a2 + a3);
  a += __shfl_xor(a, 1); a += __shfl_xor(a, 2);   // reduce quarters -> q==0 holds value
  float other = __shfl_xor(a, 4);                 // partner k (kp flipped)
  if (q == 0 && kp == 0) {
    unsigned int lo = f2bfu(a), hi = f2bfu(other);
    wbT32[(size_t)n*1536 + k2] = lo | (hi << 16);
  }
}

// ---------------- kmain_mfma (R13 verbatim): one independent wave-job = 64 rows x 256 k ----
__global__ __launch_bounds__(256) void kmain_mfma(
    const float* __restrict__ nf, const float* __restrict__ intf,
    const unsigned short* __restrict__ wbT, float* __restrict__ ndp, float* __restrict__ edp) {
  __shared__ float red[4][1600];           // wave-private transpose buffers (25.6 KB)
  const int tid = threadIdx.x;
  const int l = tid & 63;
  const int w = tid >> 6;
  const int wid = blockIdx.x*4 + w;        // 2816 wave-jobs
  const bool isNode = wid < 1024;

  int rg, chunk, kbase;
  if (isNode) { rg = wid >> 3; chunk = wid & 7; kbase = 0; }
  else        { int e = wid - 1024; rg = e >> 2; chunk = e & 3; kbase = 2048; }
  const int R0 = rg*64;
  const int kd0 = chunk*256;

  const int ln = l & 15, lg = l >> 4;

  const float* xp[4];
#pragma unroll
  for (int i = 0; i < 4; ++i) {
    int grow = R0 + i*16 + ln;
    const float* rp;
    if (isNode) rp = nf + (size_t)grow*2048;
    else {
      int b = grow / 28, p = grow - b*28;
      rp = intf + (size_t)(b*64 + d_pi[p]*8 + d_pj[p])*1024;
    }
    xp[i] = rp + kd0 + lg*8;
  }
  const unsigned short* wp0 = wbT + (size_t)ln*3072 + kbase + kd0 + lg*8;
  const unsigned short* wp1 = wp0 + (size_t)16*3072;

  f32x4 acc[4][2];
#pragma unroll
  for (int i = 0; i < 4; ++i) {
    acc[i][0] = (f32x4){0.f, 0.f, 0.f, 0.f};
    acc[i][1] = (f32x4){0.f, 0.f, 0.f, 0.f};
  }

#pragma unroll 2
  for (int t = 0; t < 8; ++t) {
    const int ko = t*32;
    bf16x8 b0 = *(const bf16x8*)(wp0 + ko);
    bf16x8 b1 = *(const bf16x8*)(wp1 + ko);
#pragma unroll
    for (int i = 0; i < 4; ++i) {
      float4 xa = *(const float4*)(xp[i] + ko);
      float4 xb = *(const float4*)(xp[i] + ko + 4);
      bf16x8 a;
      a[0] = f2bf(xa.x); a[1] = f2bf(xa.y); a[2] = f2bf(xa.z); a[3] = f2bf(xa.w);
      a[4] = f2bf(xb.x); a[5] = f2bf(xb.y); a[6] = f2bf(xb.z); a[7] = f2bf(xb.w);
      acc[i][0] = __builtin_amdgcn_mfma_f32_16x16x32_bf16(a, b0, acc[i][0], 0, 0, 0);
      acc[i][1] = __builtin_amdgcn_mfma_f32_16x16x32_bf16(a, b1, acc[i][1], 0, 0, 0);
    }
  }

  float* rw = red[w];
#pragma unroll
  for (int i = 0; i < 4; ++i)
#pragma unroll
    for (int tn = 0; tn < 2; ++tn) {
      int n = tn*16 + ln;
      if (n < 23) {
#pragma unroll
        for (int r = 0; r < 4; ++r)
          rw[(i*16 + lg*4 + r)*25 + n] = acc[i][tn][r];
      }
    }
  __syncthreads();
  float* outp = isNode ? (ndp + ((size_t)chunk*8192  + R0)*23)
                       : (edp + ((size_t)chunk*28672 + R0)*23);
#pragma unroll
  for (int i = 0; i < 23; ++i) {
    int g = i*64 + l;
    int r = g / 23, n = g - r*23;
    outp[g] = rw[r*25 + n];
  }
}

// ---------------- kcombine: one batch per block; sums 8 node / 4 edge partials ----------------
__global__ __launch_bounds__(256) void kcombine(
    const float* __restrict__ ndp, const float* __restrict__ edp,
    const float* __restrict__ bbig, const int* __restrict__ opairs,
    float* __restrict__ out) {
  __shared__ float snd[184];
  __shared__ int spos[8];
  int b = blockIdx.x, tid = threadIdx.x;
  if (tid < 184) {
    int o = tid / 23, n = tid % 23;
    float s = 0.f;
#pragma unroll
    for (int c = 0; c < 8; ++c)
      s += ndp[((size_t)c*8192 + b*8 + o)*23 + n];
    snd[tid] = s;
  } else if (tid < 192) {
    int r = tid - 184;
    int oi = opairs[b*16 + r*2], oj = opairs[b*16 + r*2 + 1];
    int a = min(oi, oj), bb = max(oi, oj);
    spos[r] = 7*a - (a*(a+1))/2 + bb - 1;
  }
  __syncthreads();
  for (int g = tid; g < 644; g += 256) {
    int p = g / 23, n = g % 23;
    float ed = 0.f;
#pragma unroll
    for (int c = 0; c < 4; ++c)
      ed += edp[((size_t)c*28672 + b*28 + p)*23 + n];
    float val = 0.5f*(snd[d_pi[p]*23 + n] + snd[d_pj[p]*23 + n]) + ed + bbig[n];
    int slot = -1, below = 0;
#pragma unroll
    for (int r = 0; r < 8; ++r) {
      int pl = spos[r];
      slot = (pl == p) ? r : slot;
      below += (pl < p) ? 1 : 0;
    }
    if (n == 0) {
      out[OUT_IND + b*28 + p] = 1.f/(1.f + expf(-val));
      out[OUT_LAB + b*28 + p] = (slot >= 0) ? 1.f : 0.f;
    } else {
      int h = n - 1;
      if (slot >= 0) {
        int rr = b*8 + slot;
        if (h < 5)      out[OUT_LRP + rr*5  + h]     = val;
        else if (h < 8) out[OUT_CRP + rr*3  + (h-5)] = val;
        else            out[OUT_MRP + rr*14 + (h-8)] = val;
      } else {
        int s = p - below;
        int rr = b*20 + s;
        if (h < 5)      out[OUT_LRN + rr*5  + h]     = val;
        else if (h < 8) out[OUT_CRN + rr*3  + (h-5)] = val;
        else            out[OUT_MRN + rr*14 + (h-8)] = val;
      }
    }
  }
}

extern "C" void kernel_launch(void* const* d_in, const int* in_sizes, int n_in,
                              void* d_out, int out_size, void* d_ws, size_t ws_size,
                              hipStream_t stream) {
  const float* nf     = (const float*)d_in[0];
  const float* intf   = (const float*)d_in[1];
  const int*   opairs = (const int*)d_in[2];
  const float* w_ind1 = (const float*)d_in[3];
  const float* b_ind1 = (const float*)d_in[4];
  const float* w_ind2 = (const float*)d_in[5];
  const float* b_ind2 = (const float*)d_in[6];
  const float* w_rel  = (const float*)d_in[7];
  const float* b_rel  = (const float*)d_in[8];
  const float* w_cr   = (const float*)d_in[9];
  const float* b_cr   = (const float*)d_in[10];
  const float* w_lr   = (const float*)d_in[11];
  const float* b_lr   = (const float*)d_in[12];
  const float* w_mr   = (const float*)d_in[13];
  const float* b_mr   = (const float*)d_in[14];
  float* out = (float*)d_out;
  float* ws  = (float*)d_ws;

  float*          bmat  = ws + WS_BMAT;
  float*          bbig  = ws + WS_BBIG;
  unsigned int*   wbT32 = (unsigned int*)(ws + WS_WBT);
  unsigned short* wbT   = (unsigned short*)(ws + WS_WBT);
  float*          ndp   = ws + WS_ND;
  float*          edp   = ws + WS_ED;

  prep1<<<177, 256, 0, stream>>>(w_rel, w_ind2, w_lr, w_cr, w_mr,
                                 b_ind1, b_ind2, b_rel, b_lr, b_cr, b_mr, bmat, bbig);
  prep2<<<1536, 256, 0, stream>>>(w_ind1, w_rel, bmat, wbT32);
  kmain_mfma<<<704, 256, 0, stream>>>(nf, intf, wbT, ndp, edp);
  kcombine<<<1024, 256, 0, stream>>>(ndp, edp, bbig, opairs, out);
}